// Round 6
// baseline (449.438 us; speedup 1.0000x reference)
//
#include <hip/hip_runtime.h>
#include <hip/hip_bf16.h>

#define BB 16
#define NN 2048
#define FIN 256
#define FO 64

typedef __bf16 bf16x8 __attribute__((ext_vector_type(8)));
typedef float  f32x4  __attribute__((ext_vector_type(4)));
typedef int    i32x4  __attribute__((ext_vector_type(4)));
typedef unsigned int uint;

// ---------------- K_PRE: fused [k1 GEMM blocks 0..511] + [pack blocks 512..33279]
// k1 blocks are dispatched FIRST so they start immediately; the 32768 pack
// blocks stream adj (268 MB) around them. k1 (~18 us) hides under the ~50 us
// stream. Pack writes 1 byte per 8 adj ints (linear bit order, j-major).
__global__ __launch_bounds__(256) void k_pre(
    const float* __restrict__ x, const float* __restrict__ weight,
    const float* __restrict__ w2, const int* __restrict__ adj,
    __bf16* __restrict__ hT, float* __restrict__ s_src, float* __restrict__ s_dst,
    unsigned char* __restrict__ mask) {
    if (blockIdx.x >= 512) {
        // ---- pack path ----
        size_t t = (size_t)(blockIdx.x - 512) * 256 + threadIdx.x;
        const i32x4* ap = (const i32x4*)(adj + t * 8);
        i32x4 a0 = __builtin_nontemporal_load(ap);
        i32x4 a1 = __builtin_nontemporal_load(ap + 1);
        unsigned bb = (unsigned)(a0.x > 0) | ((unsigned)(a0.y > 0) << 1) |
                      ((unsigned)(a0.z > 0) << 2) | ((unsigned)(a0.w > 0) << 3) |
                      ((unsigned)(a1.x > 0) << 4) | ((unsigned)(a1.y > 0) << 5) |
                      ((unsigned)(a1.z > 0) << 6) | ((unsigned)(a1.w > 0) << 7);
        mask[t] = (unsigned char)bb;
        return;
    }
    // ---- k1 GEMM path ----
    __shared__ __bf16 WtL[FO * 264];
    __shared__ float vsL[FIN], vdL[FIN];
    int t = threadIdx.x;
    {
        const float4* wr = (const float4*)(weight + t * FO);
        float a = 0.f, d = 0.f;
#pragma unroll
        for (int c = 0; c < 16; ++c) {
            float4 v = wr[c];
            int o = c * 4;
            WtL[(o + 0) * 264 + t] = (__bf16)v.x;
            WtL[(o + 1) * 264 + t] = (__bf16)v.y;
            WtL[(o + 2) * 264 + t] = (__bf16)v.z;
            WtL[(o + 3) * 264 + t] = (__bf16)v.w;
            a += v.x * w2[o] + v.y * w2[o + 1] + v.z * w2[o + 2] + v.w * w2[o + 3];
            d += v.x * w2[FO + o] + v.y * w2[FO + o + 1] +
                 v.z * w2[FO + o + 2] + v.w * w2[FO + o + 3];
        }
        vsL[t] = a;
        vdL[t] = d;
    }
    __syncthreads();

    int lane = threadIdx.x & 63, w = threadIdx.x >> 6;
    int quad = lane >> 4, m = lane & 15;
    int Rbase = blockIdx.x * 64 + w * 16;
    int R = Rbase + m;
    const float* xr = x + (long)R * FIN;

    f32x4 acc[4] = {};
    float ps = 0.f, pd = 0.f;

#pragma unroll
    for (int k0 = 0; k0 < FIN; k0 += 32) {
        int kb = k0 + quad * 8;
        float4 x0 = *(const float4*)(xr + kb);
        float4 x1 = *(const float4*)(xr + kb + 4);
        float4 u0 = *(const float4*)(vsL + kb);
        float4 u1 = *(const float4*)(vsL + kb + 4);
        float4 t0 = *(const float4*)(vdL + kb);
        float4 t1 = *(const float4*)(vdL + kb + 4);
        ps += x0.x * u0.x + x0.y * u0.y + x0.z * u0.z + x0.w * u0.w +
              x1.x * u1.x + x1.y * u1.y + x1.z * u1.z + x1.w * u1.w;
        pd += x0.x * t0.x + x0.y * t0.y + x0.z * t0.z + x0.w * t0.w +
              x1.x * t1.x + x1.y * t1.y + x1.z * t1.z + x1.w * t1.w;
        bf16x8 bf = {(__bf16)x0.x, (__bf16)x0.y, (__bf16)x0.z, (__bf16)x0.w,
                     (__bf16)x1.x, (__bf16)x1.y, (__bf16)x1.z, (__bf16)x1.w};
#pragma unroll
        for (int ot = 0; ot < 4; ++ot) {
            bf16x8 af = *(const bf16x8*)(WtL + (ot * 16 + m) * 264 + kb);
            acc[ot] = __builtin_amdgcn_mfma_f32_16x16x32_bf16(af, bf, acc[ot], 0, 0, 0);
        }
    }
    ps += __shfl_xor(ps, 16);
    ps += __shfl_xor(ps, 32);
    pd += __shfl_xor(pd, 16);
    pd += __shfl_xor(pd, 32);
    if (quad == 0) {
        s_src[R] = ps;
        s_dst[R] = pd;
    }
    int b = R >> 11;
    int nb = Rbase & (NN - 1);
#pragma unroll
    for (int ot = 0; ot < 4; ++ot) {
#pragma unroll
        for (int r = 0; r < 4; ++r) {
            int o = ot * 16 + quad * 4 + r;
            hT[((long)b * FO + o) * NN + nb + m] = (__bf16)acc[ot][r];
        }
    }
}

// ---------------- K2: masked-softmax + PV from bitmask -----------------------
// grid = 512; block = 4 waves; wave owns 16 i-rows. Zero in-loop barriers.
// Mask: dword ks of row's 256-byte mask holds all 4 quad-bytes; each lane
// loads the dword (quad-broadcast, L1) and extracts byte q statically — no
// shuffles. 4 groups x (4 uint4 mask loads + 16 k-steps) so group g+1 loads
// pipeline over group g MFMAs.
// Numerics: softmax scale-invariance — p' = mask ? fmax(E_j, cK) : 0 with
// E_j = exp(sd_j - mx) (LDS), cK = exp(-(ssr+mx)); no exp/mul in loop.
// Denominator via 5th MFMA against ones (C-layout, no epilogue shuffles).
__global__ __launch_bounds__(256, 2) void k2_attn(
    const unsigned char* __restrict__ mask, const float* __restrict__ s_src,
    const float* __restrict__ s_dst, const __bf16* __restrict__ hT,
    float* __restrict__ out) {
    __shared__ float EL[NN];  // exp(sd_j - mx), 8 KB
    int b = blockIdx.x >> 5;
    int i0 = (blockIdx.x & 31) << 6;
    int lane = threadIdx.x & 63, w = threadIdx.x >> 6;
    int quad = lane >> 4, m = lane & 15;
    int rowbase = i0 + w * 16;
    int row = rowbase + m;

    const float* sd = s_dst + b * NN;
    // wave max of s_dst (bitwise-identical across waves -> consistent EL,
    // benign redundant fill, no barrier needed)
    float mx = -3.0e38f;
    for (int j = lane; j < NN; j += 64) mx = fmaxf(mx, sd[j]);
#pragma unroll
    for (int off = 32; off >= 1; off >>= 1) mx = fmaxf(mx, __shfl_xor(mx, off));
    for (int t = lane; t < NN; t += 64) EL[t] = __expf(sd[t] - mx);

    float T = s_src[b * NN + row] + mx;
    float cK = __expf(-T);  // relu floor in the 1/K-scaled space

    const uint4* mrow = (const uint4*)(mask + ((size_t)(b * NN + row)) * 256);
    const __bf16* hTb = hT + (long)b * FO * NN;
    int q8 = quad * 8;

    f32x4 acc[4] = {};
    f32x4 accL = {};
    const bf16x8 ones = {(__bf16)1.f, (__bf16)1.f, (__bf16)1.f, (__bf16)1.f,
                         (__bf16)1.f, (__bf16)1.f, (__bf16)1.f, (__bf16)1.f};

#pragma unroll
    for (int g = 0; g < 4; ++g) {
        uint4 mv0 = mrow[g * 4 + 0];
        uint4 mv1 = mrow[g * 4 + 1];
        uint4 mv2 = mrow[g * 4 + 2];
        uint4 mv3 = mrow[g * 4 + 3];
        uint mg[16] = {mv0.x, mv0.y, mv0.z, mv0.w, mv1.x, mv1.y, mv1.z, mv1.w,
                       mv2.x, mv2.y, mv2.z, mv2.w, mv3.x, mv3.y, mv3.z, mv3.w};
#pragma unroll
        for (int u = 0; u < 16; ++u) {
            int ks = g * 16 + u;
            uint mb = (mg[u] >> (q8)) & 0xffu;  // byte q of dword ks
            const float* ep = EL + ks * 32 + q8;
            float4 e0 = *(const float4*)ep;
            float4 e1 = *(const float4*)(ep + 4);
            float p0 = (mb & 1u)   ? fmaxf(e0.x, cK) : 0.f;
            float p1 = (mb & 2u)   ? fmaxf(e0.y, cK) : 0.f;
            float p2 = (mb & 4u)   ? fmaxf(e0.z, cK) : 0.f;
            float p3 = (mb & 8u)   ? fmaxf(e0.w, cK) : 0.f;
            float p4 = (mb & 16u)  ? fmaxf(e1.x, cK) : 0.f;
            float p5 = (mb & 32u)  ? fmaxf(e1.y, cK) : 0.f;
            float p6 = (mb & 64u)  ? fmaxf(e1.z, cK) : 0.f;
            float p7 = (mb & 128u) ? fmaxf(e1.w, cK) : 0.f;
            bf16x8 af = {(__bf16)p0, (__bf16)p1, (__bf16)p2, (__bf16)p3,
                         (__bf16)p4, (__bf16)p5, (__bf16)p6, (__bf16)p7};
            accL = __builtin_amdgcn_mfma_f32_16x16x32_bf16(af, ones, accL, 0, 0, 0);
            const __bf16* hb = hTb + ks * 32 + q8;
#pragma unroll
            for (int ot = 0; ot < 4; ++ot) {
                bf16x8 bf = *(const bf16x8*)(hb + (ot * 16 + m) * NN);
                acc[ot] = __builtin_amdgcn_mfma_f32_16x16x32_bf16(af, bf, acc[ot], 0, 0, 0);
            }
        }
    }

    // epilogue: D layout col=lane&15 (o), row=quad*4+r (i-local); accL[r]=denom
    float* outp = out + ((long)b * NN + rowbase) * FO;
#pragma unroll
    for (int r = 0; r < 4; ++r) {
        int orow = quad * 4 + r;
        float inv = 1.0f / accL[r];
#pragma unroll
        for (int ot = 0; ot < 4; ++ot) {
            outp[(long)orow * FO + ot * 16 + m] = acc[ot][r] * inv;
        }
    }
}

extern "C" void kernel_launch(void* const* d_in, const int* in_sizes, int n_in,
                              void* d_out, int out_size, void* d_ws, size_t ws_size,
                              hipStream_t stream) {
    const float* x      = (const float*)d_in[0];
    const int*   adj    = (const int*)d_in[1];
    const float* weight = (const float*)d_in[2];
    const float* w2     = (const float*)d_in[3];
    float* out = (float*)d_out;

    char* ws = (char*)d_ws;
    __bf16* hT   = (__bf16*)ws;                              // 4 MB
    float* s_src = (float*)(ws + 4194304);                   // 128 KB
    float* s_dst = (float*)(ws + 4194304 + 131072);          // 128 KB
    unsigned char* mask = (unsigned char*)(ws + 4194304 + 262144);  // 8 MB

    k_pre<<<33280, 256, 0, stream>>>(x, weight, w2, adj, hT, s_src, s_dst, mask);
    k2_attn<<<512, 256, 0, stream>>>(mask, s_src, s_dst, hT, out);
}

// Round 7
// 439.053 us; speedup vs baseline: 1.0237x; 1.0237x over previous
//
#include <hip/hip_runtime.h>
#include <hip/hip_bf16.h>

#define BB 16
#define NN 2048
#define FIN 256
#define FO 64

typedef __bf16 bf16x8 __attribute__((ext_vector_type(8)));
typedef float  f32x4  __attribute__((ext_vector_type(4)));
typedef int    i32x4  __attribute__((ext_vector_type(4)));
typedef unsigned int uint;

// ---------------- K_PACK: adj int32 -> 1-bit mask (268 MB -> 8.4 MB) ---------
// Lean pure stream: tiny VGPR/zero LDS so it runs at full occupancy. This is
// the latency-tolerant form of the adj read (R4-measured best; both fusion
// attempts R5/R6 regressed by starving this stream of waves).
__global__ __launch_bounds__(256) void k_pack(const int* __restrict__ adj,
                                              unsigned char* __restrict__ mask) {
    size_t t = (size_t)blockIdx.x * 256 + threadIdx.x;
    const i32x4* ap = (const i32x4*)(adj + t * 8);
    i32x4 a0 = __builtin_nontemporal_load(ap);
    i32x4 a1 = __builtin_nontemporal_load(ap + 1);
    unsigned b = (unsigned)(a0.x > 0) | ((unsigned)(a0.y > 0) << 1) |
                 ((unsigned)(a0.z > 0) << 2) | ((unsigned)(a0.w > 0) << 3) |
                 ((unsigned)(a1.x > 0) << 4) | ((unsigned)(a1.y > 0) << 5) |
                 ((unsigned)(a1.z > 0) << 6) | ((unsigned)(a1.w > 0) << 7);
    mask[t] = (unsigned char)b;
}

// ---------------- K1: h GEMM (MFMA bf16) + exact fp32 s_src/s_dst ------------
__global__ __launch_bounds__(256) void k1_gemm(
    const float* __restrict__ x, const float* __restrict__ weight,
    const float* __restrict__ w2,
    __bf16* __restrict__ hT, float* __restrict__ s_src, float* __restrict__ s_dst) {
    __shared__ __bf16 WtL[FO * 264];
    __shared__ float vsL[FIN], vdL[FIN];
    int t = threadIdx.x;
    {
        const float4* wr = (const float4*)(weight + t * FO);
        float a = 0.f, d = 0.f;
#pragma unroll
        for (int c = 0; c < 16; ++c) {
            float4 v = wr[c];
            int o = c * 4;
            WtL[(o + 0) * 264 + t] = (__bf16)v.x;
            WtL[(o + 1) * 264 + t] = (__bf16)v.y;
            WtL[(o + 2) * 264 + t] = (__bf16)v.z;
            WtL[(o + 3) * 264 + t] = (__bf16)v.w;
            a += v.x * w2[o] + v.y * w2[o + 1] + v.z * w2[o + 2] + v.w * w2[o + 3];
            d += v.x * w2[FO + o] + v.y * w2[FO + o + 1] +
                 v.z * w2[FO + o + 2] + v.w * w2[FO + o + 3];
        }
        vsL[t] = a;
        vdL[t] = d;
    }
    __syncthreads();

    int lane = threadIdx.x & 63, w = threadIdx.x >> 6;
    int quad = lane >> 4, m = lane & 15;
    int Rbase = blockIdx.x * 64 + w * 16;
    int R = Rbase + m;
    const float* xr = x + (long)R * FIN;

    f32x4 acc[4] = {};
    float ps = 0.f, pd = 0.f;

#pragma unroll
    for (int k0 = 0; k0 < FIN; k0 += 32) {
        int kb = k0 + quad * 8;
        float4 x0 = *(const float4*)(xr + kb);
        float4 x1 = *(const float4*)(xr + kb + 4);
        float4 u0 = *(const float4*)(vsL + kb);
        float4 u1 = *(const float4*)(vsL + kb + 4);
        float4 t0 = *(const float4*)(vdL + kb);
        float4 t1 = *(const float4*)(vdL + kb + 4);
        ps += x0.x * u0.x + x0.y * u0.y + x0.z * u0.z + x0.w * u0.w +
              x1.x * u1.x + x1.y * u1.y + x1.z * u1.z + x1.w * u1.w;
        pd += x0.x * t0.x + x0.y * t0.y + x0.z * t0.z + x0.w * t0.w +
              x1.x * t1.x + x1.y * t1.y + x1.z * t1.z + x1.w * t1.w;
        bf16x8 bf = {(__bf16)x0.x, (__bf16)x0.y, (__bf16)x0.z, (__bf16)x0.w,
                     (__bf16)x1.x, (__bf16)x1.y, (__bf16)x1.z, (__bf16)x1.w};
#pragma unroll
        for (int ot = 0; ot < 4; ++ot) {
            bf16x8 af = *(const bf16x8*)(WtL + (ot * 16 + m) * 264 + kb);
            acc[ot] = __builtin_amdgcn_mfma_f32_16x16x32_bf16(af, bf, acc[ot], 0, 0, 0);
        }
    }
    ps += __shfl_xor(ps, 16);
    ps += __shfl_xor(ps, 32);
    pd += __shfl_xor(pd, 16);
    pd += __shfl_xor(pd, 32);
    if (quad == 0) {
        s_src[R] = ps;
        s_dst[R] = pd;
    }
    int b = R >> 11;
    int nb = Rbase & (NN - 1);
#pragma unroll
    for (int ot = 0; ot < 4; ++ot) {
#pragma unroll
        for (int r = 0; r < 4; ++r) {
            int o = ot * 16 + quad * 4 + r;
            hT[((long)b * FO + o) * NN + nb + m] = (__bf16)acc[ot][r];
        }
    }
}

// ---------------- K2: masked-softmax + PV from bitmask, 1-wave blocks --------
// grid = 16 b * 128 itiles = 2048 blocks; block = ONE wave owning 16 i-rows.
// 8 KB LDS + ~90 VGPR -> up to 20 waves/CU (vs 8 at the old 512-block grid):
// the k-loop stalls on 4 L2-latency hT loads per step, so waves-in-flight is
// the limiter. Mask: dword ks of a row's 256-byte mask holds all 4 quad-bytes;
// lanes of a quad-column read the same dword (no shuffles). Numerics: softmax
// scale-invariance -> p = mask ? fmax(E_j, cK) : 0, E_j = exp(sd_j - mx) in
// LDS, cK = exp(-(ssr+mx)); no exp/mul in the loop. Denominator via 5th MFMA
// against ones (C-layout, no epilogue shuffles).
__global__ __launch_bounds__(64, 4) void k2_attn(
    const unsigned char* __restrict__ mask, const float* __restrict__ s_src,
    const float* __restrict__ s_dst, const __bf16* __restrict__ hT,
    float* __restrict__ out) {
    __shared__ float EL[NN];  // exp(sd_j - mx), 8 KB
    int b = blockIdx.x >> 7;
    int rowbase = (blockIdx.x & 127) << 4;
    int lane = threadIdx.x & 63;
    int quad = lane >> 4, m = lane & 15;
    int row = rowbase + m;

    const float* sd = s_dst + b * NN;
    float mx = -3.0e38f;
    for (int j = lane; j < NN; j += 64) mx = fmaxf(mx, sd[j]);
#pragma unroll
    for (int off = 32; off >= 1; off >>= 1) mx = fmaxf(mx, __shfl_xor(mx, off));
    for (int t = lane; t < NN; t += 64) EL[t] = __expf(sd[t] - mx);
    // single wave: LDS writes visible after lgkmcnt drain, no barrier needed

    float T = s_src[b * NN + row] + mx;
    float cK = __expf(-T);  // relu floor in the 1/K-scaled space

    const uint4* mrow = (const uint4*)(mask + ((size_t)(b * NN + row)) * 256);
    const __bf16* hTb = hT + (long)b * FO * NN;
    int q8 = quad * 8;

    f32x4 acc[4] = {};
    f32x4 accL = {};
    const bf16x8 ones = {(__bf16)1.f, (__bf16)1.f, (__bf16)1.f, (__bf16)1.f,
                         (__bf16)1.f, (__bf16)1.f, (__bf16)1.f, (__bf16)1.f};

#pragma unroll
    for (int g = 0; g < 4; ++g) {
        uint4 mv0 = mrow[g * 4 + 0];
        uint4 mv1 = mrow[g * 4 + 1];
        uint4 mv2 = mrow[g * 4 + 2];
        uint4 mv3 = mrow[g * 4 + 3];
        uint mg[16] = {mv0.x, mv0.y, mv0.z, mv0.w, mv1.x, mv1.y, mv1.z, mv1.w,
                       mv2.x, mv2.y, mv2.z, mv2.w, mv3.x, mv3.y, mv3.z, mv3.w};
#pragma unroll
        for (int u = 0; u < 16; ++u) {
            int ks = g * 16 + u;
            uint mb = (mg[u] >> q8) & 0xffu;  // byte 'quad' of dword ks
            const float* ep = EL + ks * 32 + q8;
            float4 e0 = *(const float4*)ep;
            float4 e1 = *(const float4*)(ep + 4);
            float p0 = (mb & 1u)   ? fmaxf(e0.x, cK) : 0.f;
            float p1 = (mb & 2u)   ? fmaxf(e0.y, cK) : 0.f;
            float p2 = (mb & 4u)   ? fmaxf(e0.z, cK) : 0.f;
            float p3 = (mb & 8u)   ? fmaxf(e0.w, cK) : 0.f;
            float p4 = (mb & 16u)  ? fmaxf(e1.x, cK) : 0.f;
            float p5 = (mb & 32u)  ? fmaxf(e1.y, cK) : 0.f;
            float p6 = (mb & 64u)  ? fmaxf(e1.z, cK) : 0.f;
            float p7 = (mb & 128u) ? fmaxf(e1.w, cK) : 0.f;
            bf16x8 af = {(__bf16)p0, (__bf16)p1, (__bf16)p2, (__bf16)p3,
                         (__bf16)p4, (__bf16)p5, (__bf16)p6, (__bf16)p7};
            accL = __builtin_amdgcn_mfma_f32_16x16x32_bf16(af, ones, accL, 0, 0, 0);
            const __bf16* hb = hTb + ks * 32 + q8;
#pragma unroll
            for (int ot = 0; ot < 4; ++ot) {
                bf16x8 bf = *(const bf16x8*)(hb + (ot * 16 + m) * NN);
                acc[ot] = __builtin_amdgcn_mfma_f32_16x16x32_bf16(af, bf, acc[ot], 0, 0, 0);
            }
        }
    }

    // epilogue: D layout col=lane&15 (o), row=quad*4+r (i-local); accL[r]=denom
    float* outp = out + ((long)b * NN + rowbase) * FO;
#pragma unroll
    for (int r = 0; r < 4; ++r) {
        int orow = quad * 4 + r;
        float inv = 1.0f / accL[r];
#pragma unroll
        for (int ot = 0; ot < 4; ++ot) {
            outp[(long)orow * FO + ot * 16 + m] = acc[ot][r] * inv;
        }
    }
}

extern "C" void kernel_launch(void* const* d_in, const int* in_sizes, int n_in,
                              void* d_out, int out_size, void* d_ws, size_t ws_size,
                              hipStream_t stream) {
    const float* x      = (const float*)d_in[0];
    const int*   adj    = (const int*)d_in[1];
    const float* weight = (const float*)d_in[2];
    const float* w2     = (const float*)d_in[3];
    float* out = (float*)d_out;

    char* ws = (char*)d_ws;
    __bf16* hT   = (__bf16*)ws;                              // 4 MB
    float* s_src = (float*)(ws + 4194304);                   // 128 KB
    float* s_dst = (float*)(ws + 4194304 + 131072);          // 128 KB
    unsigned char* mask = (unsigned char*)(ws + 4194304 + 262144);  // 8 MB

    k_pack<<<32768, 256, 0, stream>>>(adj, mask);
    k1_gemm<<<512, 256, 0, stream>>>(x, weight, w2, hT, s_src, s_dst);
    k2_attn<<<2048, 64, 0, stream>>>(mask, s_src, s_dst, hT, out);
}

// Round 8
// 423.981 us; speedup vs baseline: 1.0600x; 1.0355x over previous
//
#include <hip/hip_runtime.h>
#include <hip/hip_bf16.h>

#define BB 16
#define NN 2048
#define FIN 256
#define FO 64
#define CH 256        // k2 j-chunk
#define HSTR 264      // LDS hT row stride (bf16) — pad breaks bank aliasing

typedef __bf16 bf16x8 __attribute__((ext_vector_type(8)));
typedef float  f32x4  __attribute__((ext_vector_type(4)));
typedef int    i32x4  __attribute__((ext_vector_type(4)));
typedef unsigned int uint;
typedef unsigned short ushort;

// ---------------- K_PACK: adj int32 -> 1-bit mask (268 MB -> 8.4 MB) ---------
// Lean stream, 64 B/thread (4 independent dwordx4 in flight), ushort stores.
__global__ __launch_bounds__(256) void k_pack(const int* __restrict__ adj,
                                              ushort* __restrict__ mask) {
    size_t t = (size_t)blockIdx.x * 256 + threadIdx.x;
    const i32x4* ap = (const i32x4*)(adj + t * 16);
    i32x4 a0 = ap[0], a1 = ap[1], a2 = ap[2], a3 = ap[3];
    uint b = (uint)(a0.x > 0) | ((uint)(a0.y > 0) << 1) |
             ((uint)(a0.z > 0) << 2) | ((uint)(a0.w > 0) << 3) |
             ((uint)(a1.x > 0) << 4) | ((uint)(a1.y > 0) << 5) |
             ((uint)(a1.z > 0) << 6) | ((uint)(a1.w > 0) << 7) |
             ((uint)(a2.x > 0) << 8) | ((uint)(a2.y > 0) << 9) |
             ((uint)(a2.z > 0) << 10) | ((uint)(a2.w > 0) << 11) |
             ((uint)(a3.x > 0) << 12) | ((uint)(a3.y > 0) << 13) |
             ((uint)(a3.z > 0) << 14) | ((uint)(a3.w > 0) << 15);
    mask[t] = (ushort)b;
}

// ---------------- K1: h GEMM (MFMA bf16) + exact fp32 s_src/s_dst ------------
__global__ __launch_bounds__(256) void k1_gemm(
    const float* __restrict__ x, const float* __restrict__ weight,
    const float* __restrict__ w2,
    __bf16* __restrict__ hT, float* __restrict__ s_src, float* __restrict__ s_dst) {
    __shared__ __bf16 WtL[FO * 264];
    __shared__ float vsL[FIN], vdL[FIN];
    int t = threadIdx.x;
    {
        const float4* wr = (const float4*)(weight + t * FO);
        float a = 0.f, d = 0.f;
#pragma unroll
        for (int c = 0; c < 16; ++c) {
            float4 v = wr[c];
            int o = c * 4;
            WtL[(o + 0) * 264 + t] = (__bf16)v.x;
            WtL[(o + 1) * 264 + t] = (__bf16)v.y;
            WtL[(o + 2) * 264 + t] = (__bf16)v.z;
            WtL[(o + 3) * 264 + t] = (__bf16)v.w;
            a += v.x * w2[o] + v.y * w2[o + 1] + v.z * w2[o + 2] + v.w * w2[o + 3];
            d += v.x * w2[FO + o] + v.y * w2[FO + o + 1] +
                 v.z * w2[FO + o + 2] + v.w * w2[FO + o + 3];
        }
        vsL[t] = a;
        vdL[t] = d;
    }
    __syncthreads();

    int lane = threadIdx.x & 63, w = threadIdx.x >> 6;
    int quad = lane >> 4, m = lane & 15;
    int Rbase = blockIdx.x * 64 + w * 16;
    int R = Rbase + m;
    const float* xr = x + (long)R * FIN;

    f32x4 acc[4] = {};
    float ps = 0.f, pd = 0.f;

#pragma unroll
    for (int k0 = 0; k0 < FIN; k0 += 32) {
        int kb = k0 + quad * 8;
        float4 x0 = *(const float4*)(xr + kb);
        float4 x1 = *(const float4*)(xr + kb + 4);
        float4 u0 = *(const float4*)(vsL + kb);
        float4 u1 = *(const float4*)(vsL + kb + 4);
        float4 t0 = *(const float4*)(vdL + kb);
        float4 t1 = *(const float4*)(vdL + kb + 4);
        ps += x0.x * u0.x + x0.y * u0.y + x0.z * u0.z + x0.w * u0.w +
              x1.x * u1.x + x1.y * u1.y + x1.z * u1.z + x1.w * u1.w;
        pd += x0.x * t0.x + x0.y * t0.y + x0.z * t0.z + x0.w * t0.w +
              x1.x * t1.x + x1.y * t1.y + x1.z * t1.z + x1.w * t1.w;
        bf16x8 bf = {(__bf16)x0.x, (__bf16)x0.y, (__bf16)x0.z, (__bf16)x0.w,
                     (__bf16)x1.x, (__bf16)x1.y, (__bf16)x1.z, (__bf16)x1.w};
#pragma unroll
        for (int ot = 0; ot < 4; ++ot) {
            bf16x8 af = *(const bf16x8*)(WtL + (ot * 16 + m) * 264 + kb);
            acc[ot] = __builtin_amdgcn_mfma_f32_16x16x32_bf16(af, bf, acc[ot], 0, 0, 0);
        }
    }
    ps += __shfl_xor(ps, 16);
    ps += __shfl_xor(ps, 32);
    pd += __shfl_xor(pd, 16);
    pd += __shfl_xor(pd, 32);
    if (quad == 0) {
        s_src[R] = ps;
        s_dst[R] = pd;
    }
    int b = R >> 11;
    int nb = Rbase & (NN - 1);
#pragma unroll
    for (int ot = 0; ot < 4; ++ot) {
#pragma unroll
        for (int r = 0; r < 4; ++r) {
            int o = ot * 16 + quad * 4 + r;
            hT[((long)b * FO + o) * NN + nb + m] = (__bf16)acc[ot][r];
        }
    }
}

// ---------------- K2: masked-softmax + PV, LDS-shared hT chunks --------------
// grid = 16 b * 32 itiles = 512 blocks; block = 4 waves = 64 i-rows.
// KEY: all 4 waves share one LDS-staged hT chunk [64 o x 256 j] (32 KB),
// cutting hT L2 traffic 512 MB -> 128 MB (the measured-inferred k2 limiter:
// 16 B L2-latency-bound reads at ~5.5 TB/s effective). Staging = 8 wide
// dwordx4/thread (deep MLP); MFMA B-frags via ds_read_b128 (stride-264 pad).
// Numerics (R6/R7, passing): p = mask ? fmax(EL[j], cK) : 0 with
// EL[j] = exp(sd_j - mx), cK = exp(-(s_src_i + mx)); denom via ones-MFMA.
__global__ __launch_bounds__(256, 4) void k2_attn(
    const unsigned char* __restrict__ mask, const float* __restrict__ s_src,
    const float* __restrict__ s_dst, const __bf16* __restrict__ hT,
    float* __restrict__ out) {
    __shared__ __bf16 hL[FO * HSTR];  // 33 KB
    __shared__ float EL[NN];          // 8 KB
    int b = blockIdx.x >> 5;
    int i0 = (blockIdx.x & 31) << 6;
    int lane = threadIdx.x & 63, w = threadIdx.x >> 6;
    int quad = lane >> 4, m = lane & 15;
    int rowbase = i0 + w * 16;
    int row = rowbase + m;

    const float* sd = s_dst + b * NN;
    // per-wave mx (bitwise-identical across waves)
    float mx = -3.0e38f;
    for (int j = lane; j < NN; j += 64) mx = fmaxf(mx, sd[j]);
#pragma unroll
    for (int off = 32; off >= 1; off >>= 1) mx = fmaxf(mx, __shfl_xor(mx, off));
    // cooperative EL fill: thread t -> j = t*8 .. t*8+7 (covered by chunk-0 barrier)
    {
        int j0 = threadIdx.x * 8;
        float4 v0 = *(const float4*)(sd + j0);
        float4 v1 = *(const float4*)(sd + j0 + 4);
        EL[j0 + 0] = __expf(v0.x - mx);
        EL[j0 + 1] = __expf(v0.y - mx);
        EL[j0 + 2] = __expf(v0.z - mx);
        EL[j0 + 3] = __expf(v0.w - mx);
        EL[j0 + 4] = __expf(v1.x - mx);
        EL[j0 + 5] = __expf(v1.y - mx);
        EL[j0 + 6] = __expf(v1.z - mx);
        EL[j0 + 7] = __expf(v1.w - mx);
    }

    float T = s_src[b * NN + row] + mx;
    float cK = __expf(-T);  // relu floor in the scaled space

    const uint4* mrow = (const uint4*)(mask + ((size_t)(b * NN + row)) * 256);
    int q8 = quad * 8;
    int so = threadIdx.x >> 2;        // staging: this thread's o row
    int sseg = (threadIdx.x & 3) * 64;  // and j sub-segment

    f32x4 acc[4] = {};
    f32x4 accL = {};
    const bf16x8 ones = {(__bf16)1.f, (__bf16)1.f, (__bf16)1.f, (__bf16)1.f,
                         (__bf16)1.f, (__bf16)1.f, (__bf16)1.f, (__bf16)1.f};

    for (int c = 0; c < NN / CH; ++c) {
        __syncthreads();  // prev chunk's readers done (and chunk0: EL visible)
        // ---- stage hT[b][0..64)[c*CH .. c*CH+CH) -> hL (8 x dwordx4/thread) ----
        {
            const bf16x8* src =
                (const bf16x8*)(hT + ((long)b * FO + so) * NN + c * CH + sseg);
            bf16x8* dst = (bf16x8*)(hL + so * HSTR + sseg);
            bf16x8 v0 = src[0], v1 = src[1], v2 = src[2], v3 = src[3];
            bf16x8 v4 = src[4], v5 = src[5], v6 = src[6], v7 = src[7];
            dst[0] = v0; dst[1] = v1; dst[2] = v2; dst[3] = v3;
            dst[4] = v4; dst[5] = v5; dst[6] = v6; dst[7] = v7;
        }
        __syncthreads();
        // ---- mask dwords for this chunk (k-steps c*8 .. c*8+7) ----
        uint4 mv0 = mrow[c * 2], mv1 = mrow[c * 2 + 1];
        uint mg[8] = {mv0.x, mv0.y, mv0.z, mv0.w, mv1.x, mv1.y, mv1.z, mv1.w};
#pragma unroll
        for (int u = 0; u < 8; ++u) {
            int ksg = c * 8 + u;
            uint mb = (mg[u] >> q8) & 0xffu;
            const float* ep = EL + ksg * 32 + q8;
            float4 e0 = *(const float4*)ep;
            float4 e1 = *(const float4*)(ep + 4);
            float p0 = (mb & 1u)   ? fmaxf(e0.x, cK) : 0.f;
            float p1 = (mb & 2u)   ? fmaxf(e0.y, cK) : 0.f;
            float p2 = (mb & 4u)   ? fmaxf(e0.z, cK) : 0.f;
            float p3 = (mb & 8u)   ? fmaxf(e0.w, cK) : 0.f;
            float p4 = (mb & 16u)  ? fmaxf(e1.x, cK) : 0.f;
            float p5 = (mb & 32u)  ? fmaxf(e1.y, cK) : 0.f;
            float p6 = (mb & 64u)  ? fmaxf(e1.z, cK) : 0.f;
            float p7 = (mb & 128u) ? fmaxf(e1.w, cK) : 0.f;
            bf16x8 af = {(__bf16)p0, (__bf16)p1, (__bf16)p2, (__bf16)p3,
                         (__bf16)p4, (__bf16)p5, (__bf16)p6, (__bf16)p7};
            accL = __builtin_amdgcn_mfma_f32_16x16x32_bf16(af, ones, accL, 0, 0, 0);
            const __bf16* hb = hL + u * 32 + q8;
#pragma unroll
            for (int ot = 0; ot < 4; ++ot) {
                bf16x8 bf = *(const bf16x8*)(hb + (ot * 16 + m) * HSTR);
                acc[ot] = __builtin_amdgcn_mfma_f32_16x16x32_bf16(af, bf, acc[ot], 0, 0, 0);
            }
        }
    }

    // epilogue: D layout col=lane&15 (o), row=quad*4+r (i-local); accL[r]=denom
    float* outp = out + ((long)b * NN + rowbase) * FO;
#pragma unroll
    for (int r = 0; r < 4; ++r) {
        int orow = quad * 4 + r;
        float inv = 1.0f / accL[r];
#pragma unroll
        for (int ot = 0; ot < 4; ++ot) {
            outp[(long)orow * FO + ot * 16 + m] = acc[ot][r] * inv;
        }
    }
}

extern "C" void kernel_launch(void* const* d_in, const int* in_sizes, int n_in,
                              void* d_out, int out_size, void* d_ws, size_t ws_size,
                              hipStream_t stream) {
    const float* x      = (const float*)d_in[0];
    const int*   adj    = (const int*)d_in[1];
    const float* weight = (const float*)d_in[2];
    const float* w2     = (const float*)d_in[3];
    float* out = (float*)d_out;

    char* ws = (char*)d_ws;
    __bf16* hT   = (__bf16*)ws;                              // 4 MB
    float* s_src = (float*)(ws + 4194304);                   // 128 KB
    float* s_dst = (float*)(ws + 4194304 + 131072);          // 128 KB
    unsigned char* mask = (unsigned char*)(ws + 4194304 + 262144);  // 8 MB

    k_pack<<<16384, 256, 0, stream>>>(adj, (ushort*)mask);
    k1_gemm<<<512, 256, 0, stream>>>(x, weight, w2, hT, s_src, s_dst);
    k2_attn<<<512, 256, 0, stream>>>(mask, s_src, s_dst, hT, out);
}

// Round 9
// 408.018 us; speedup vs baseline: 1.1015x; 1.0391x over previous
//
#include <hip/hip_runtime.h>
#include <hip/hip_bf16.h>

#define BB 16
#define NN 2048
#define FIN 256
#define FO 64
#define CH 256        // k2 j-chunk
#define HSTR 264      // LDS hT row stride (bf16): 528 B -> 2-way-free bank stride

typedef __bf16 bf16x8 __attribute__((ext_vector_type(8)));
typedef float  f32x4  __attribute__((ext_vector_type(4)));
typedef int    i32x4  __attribute__((ext_vector_type(4)));
typedef unsigned int uint;

// ---------------- K_PACK: adj int32 -> 1-bit mask (268 MB -> 8.4 MB) ---------
// R4-exact lean stream (measured best): nt dwordx4 loads, 32 B/thread, byte
// stores, 32768 tiny blocks -> max occupancy, no L2 pollution.
__global__ __launch_bounds__(256) void k_pack(const int* __restrict__ adj,
                                              unsigned char* __restrict__ mask) {
    size_t t = (size_t)blockIdx.x * 256 + threadIdx.x;
    const i32x4* ap = (const i32x4*)(adj + t * 8);
    i32x4 a0 = __builtin_nontemporal_load(ap);
    i32x4 a1 = __builtin_nontemporal_load(ap + 1);
    unsigned b = (unsigned)(a0.x > 0) | ((unsigned)(a0.y > 0) << 1) |
                 ((unsigned)(a0.z > 0) << 2) | ((unsigned)(a0.w > 0) << 3) |
                 ((unsigned)(a1.x > 0) << 4) | ((unsigned)(a1.y > 0) << 5) |
                 ((unsigned)(a1.z > 0) << 6) | ((unsigned)(a1.w > 0) << 7);
    mask[t] = (unsigned char)b;
}

// ---------------- K1: h GEMM (MFMA bf16) + exact fp32 s_src/s_dst ------------
__global__ __launch_bounds__(256) void k1_gemm(
    const float* __restrict__ x, const float* __restrict__ weight,
    const float* __restrict__ w2,
    __bf16* __restrict__ hT, float* __restrict__ s_src, float* __restrict__ s_dst) {
    __shared__ __bf16 WtL[FO * 264];
    __shared__ float vsL[FIN], vdL[FIN];
    int t = threadIdx.x;
    {
        const float4* wr = (const float4*)(weight + t * FO);
        float a = 0.f, d = 0.f;
#pragma unroll
        for (int c = 0; c < 16; ++c) {
            float4 v = wr[c];
            int o = c * 4;
            WtL[(o + 0) * 264 + t] = (__bf16)v.x;
            WtL[(o + 1) * 264 + t] = (__bf16)v.y;
            WtL[(o + 2) * 264 + t] = (__bf16)v.z;
            WtL[(o + 3) * 264 + t] = (__bf16)v.w;
            a += v.x * w2[o] + v.y * w2[o + 1] + v.z * w2[o + 2] + v.w * w2[o + 3];
            d += v.x * w2[FO + o] + v.y * w2[FO + o + 1] +
                 v.z * w2[FO + o + 2] + v.w * w2[FO + o + 3];
        }
        vsL[t] = a;
        vdL[t] = d;
    }
    __syncthreads();

    int lane = threadIdx.x & 63, w = threadIdx.x >> 6;
    int quad = lane >> 4, m = lane & 15;
    int Rbase = blockIdx.x * 64 + w * 16;
    int R = Rbase + m;
    const float* xr = x + (long)R * FIN;

    f32x4 acc[4] = {};
    float ps = 0.f, pd = 0.f;

#pragma unroll
    for (int k0 = 0; k0 < FIN; k0 += 32) {
        int kb = k0 + quad * 8;
        float4 x0 = *(const float4*)(xr + kb);
        float4 x1 = *(const float4*)(xr + kb + 4);
        float4 u0 = *(const float4*)(vsL + kb);
        float4 u1 = *(const float4*)(vsL + kb + 4);
        float4 t0 = *(const float4*)(vdL + kb);
        float4 t1 = *(const float4*)(vdL + kb + 4);
        ps += x0.x * u0.x + x0.y * u0.y + x0.z * u0.z + x0.w * u0.w +
              x1.x * u1.x + x1.y * u1.y + x1.z * u1.z + x1.w * u1.w;
        pd += x0.x * t0.x + x0.y * t0.y + x0.z * t0.z + x0.w * t0.w +
              x1.x * t1.x + x1.y * t1.y + x1.z * t1.z + x1.w * t1.w;
        bf16x8 bf = {(__bf16)x0.x, (__bf16)x0.y, (__bf16)x0.z, (__bf16)x0.w,
                     (__bf16)x1.x, (__bf16)x1.y, (__bf16)x1.z, (__bf16)x1.w};
#pragma unroll
        for (int ot = 0; ot < 4; ++ot) {
            bf16x8 af = *(const bf16x8*)(WtL + (ot * 16 + m) * 264 + kb);
            acc[ot] = __builtin_amdgcn_mfma_f32_16x16x32_bf16(af, bf, acc[ot], 0, 0, 0);
        }
    }
    ps += __shfl_xor(ps, 16);
    ps += __shfl_xor(ps, 32);
    pd += __shfl_xor(pd, 16);
    pd += __shfl_xor(pd, 32);
    if (quad == 0) {
        s_src[R] = ps;
        s_dst[R] = pd;
    }
    int b = R >> 11;
    int nb = Rbase & (NN - 1);
#pragma unroll
    for (int ot = 0; ot < 4; ++ot) {
#pragma unroll
        for (int r = 0; r < 4; ++r) {
            int o = ot * 16 + quad * 4 + r;
            hT[((long)b * FO + o) * NN + nb + m] = (__bf16)acc[ot][r];
        }
    }
}

// ---------------- K2: masked-softmax + PV, pipelined LDS-shared hT chunks ----
// grid = 512 (2 blocks/CU); block = 4 waves = 64 i-rows sharing staged hT.
// R8 + software pipeline: chunk c+1's hT fragment (8x16 B/thread) and mask
// dwords are prefetched into REGISTERS during chunk c's MFMA phase, so the
// global-load latency that R8 exposed at each __syncthreads is covered by
// compute. vmcnt wait lands at the next ds_write, after ~500 cyc of MFMA.
__global__ __launch_bounds__(256, 2) void k2_attn(
    const unsigned char* __restrict__ mask, const float* __restrict__ s_src,
    const float* __restrict__ s_dst, const __bf16* __restrict__ hT,
    float* __restrict__ out) {
    __shared__ __bf16 hL[FO * HSTR];  // 33 KB
    __shared__ float EL[NN];          // 8 KB
    int b = blockIdx.x >> 5;
    int i0 = (blockIdx.x & 31) << 6;
    int lane = threadIdx.x & 63, w = threadIdx.x >> 6;
    int quad = lane >> 4, m = lane & 15;
    int rowbase = i0 + w * 16;
    int row = rowbase + m;

    const float* sd = s_dst + b * NN;
    // per-wave mx (bitwise-identical across waves)
    float mx = -3.0e38f;
    for (int j = lane; j < NN; j += 64) mx = fmaxf(mx, sd[j]);
#pragma unroll
    for (int off = 32; off >= 1; off >>= 1) mx = fmaxf(mx, __shfl_xor(mx, off));
    // cooperative EL fill (visible after the loop's first __syncthreads)
    {
        int j0 = threadIdx.x * 8;
        float4 v0 = *(const float4*)(sd + j0);
        float4 v1 = *(const float4*)(sd + j0 + 4);
        EL[j0 + 0] = __expf(v0.x - mx);
        EL[j0 + 1] = __expf(v0.y - mx);
        EL[j0 + 2] = __expf(v0.z - mx);
        EL[j0 + 3] = __expf(v0.w - mx);
        EL[j0 + 4] = __expf(v1.x - mx);
        EL[j0 + 5] = __expf(v1.y - mx);
        EL[j0 + 6] = __expf(v1.z - mx);
        EL[j0 + 7] = __expf(v1.w - mx);
    }

    float T = s_src[b * NN + row] + mx;
    float cK = __expf(-T);  // relu floor in the scaled space

    // staging role: thread stages row so (0..63), 128 B at col seg (tid&3)*64
    int so = threadIdx.x >> 2;
    int sc = (threadIdx.x & 3) * 64;
    const __bf16* hsrc = hT + ((long)b * FO + so) * NN + sc;
    __bf16* hdst = hL + so * HSTR + sc;

    const uint4* mrow = (const uint4*)(mask + ((size_t)(b * NN + row)) * 256);
    int q8 = quad * 8;

    // prefetch chunk 0
    bf16x8 st[8];
    {
        const bf16x8* sp = (const bf16x8*)hsrc;
#pragma unroll
        for (int i = 0; i < 8; ++i) st[i] = sp[i];
    }
    uint4 mv0 = mrow[0], mv1 = mrow[1];

    f32x4 acc[4] = {};
    f32x4 accL = {};
    const bf16x8 ones = {(__bf16)1.f, (__bf16)1.f, (__bf16)1.f, (__bf16)1.f,
                         (__bf16)1.f, (__bf16)1.f, (__bf16)1.f, (__bf16)1.f};

    for (int c = 0; c < NN / CH; ++c) {
        __syncthreads();  // prev chunk's readers done (and c=0: EL visible)
        {
            bf16x8* dp = (bf16x8*)hdst;
#pragma unroll
            for (int i = 0; i < 8; ++i) dp[i] = st[i];
        }
        __syncthreads();
        uint mg[8] = {mv0.x, mv0.y, mv0.z, mv0.w, mv1.x, mv1.y, mv1.z, mv1.w};
        if (c < NN / CH - 1) {
            // prefetch chunk c+1 into registers; consumed at next ds_write
            const bf16x8* sp = (const bf16x8*)(hsrc + (c + 1) * CH);
#pragma unroll
            for (int i = 0; i < 8; ++i) st[i] = sp[i];
            mv0 = mrow[(c + 1) * 2];
            mv1 = mrow[(c + 1) * 2 + 1];
        }
        // ---- MFMA phase chunk c ----
#pragma unroll
        for (int u = 0; u < 8; ++u) {
            int ksg = c * 8 + u;
            uint mb = (mg[u] >> q8) & 0xffu;
            const float* ep = EL + ksg * 32 + q8;
            float4 e0 = *(const float4*)ep;
            float4 e1 = *(const float4*)(ep + 4);
            float p0 = (mb & 1u)   ? fmaxf(e0.x, cK) : 0.f;
            float p1 = (mb & 2u)   ? fmaxf(e0.y, cK) : 0.f;
            float p2 = (mb & 4u)   ? fmaxf(e0.z, cK) : 0.f;
            float p3 = (mb & 8u)   ? fmaxf(e0.w, cK) : 0.f;
            float p4 = (mb & 16u)  ? fmaxf(e1.x, cK) : 0.f;
            float p5 = (mb & 32u)  ? fmaxf(e1.y, cK) : 0.f;
            float p6 = (mb & 64u)  ? fmaxf(e1.z, cK) : 0.f;
            float p7 = (mb & 128u) ? fmaxf(e1.w, cK) : 0.f;
            bf16x8 af = {(__bf16)p0, (__bf16)p1, (__bf16)p2, (__bf16)p3,
                         (__bf16)p4, (__bf16)p5, (__bf16)p6, (__bf16)p7};
            accL = __builtin_amdgcn_mfma_f32_16x16x32_bf16(af, ones, accL, 0, 0, 0);
            const __bf16* hb = hL + u * 32 + q8;
#pragma unroll
            for (int ot = 0; ot < 4; ++ot) {
                bf16x8 bf = *(const bf16x8*)(hb + (ot * 16 + m) * HSTR);
                acc[ot] = __builtin_amdgcn_mfma_f32_16x16x32_bf16(af, bf, acc[ot], 0, 0, 0);
            }
        }
    }

    // epilogue: D layout col=lane&15 (o), row=quad*4+r (i-local); accL[r]=denom
    float* outp = out + ((long)b * NN + rowbase) * FO;
#pragma unroll
    for (int r = 0; r < 4; ++r) {
        int orow = quad * 4 + r;
        float inv = 1.0f / accL[r];
#pragma unroll
        for (int ot = 0; ot < 4; ++ot) {
            outp[(long)orow * FO + ot * 16 + m] = acc[ot][r] * inv;
        }
    }
}

extern "C" void kernel_launch(void* const* d_in, const int* in_sizes, int n_in,
                              void* d_out, int out_size, void* d_ws, size_t ws_size,
                              hipStream_t stream) {
    const float* x      = (const float*)d_in[0];
    const int*   adj    = (const int*)d_in[1];
    const float* weight = (const float*)d_in[2];
    const float* w2     = (const float*)d_in[3];
    float* out = (float*)d_out;

    char* ws = (char*)d_ws;
    __bf16* hT   = (__bf16*)ws;                              // 4 MB
    float* s_src = (float*)(ws + 4194304);                   // 128 KB
    float* s_dst = (float*)(ws + 4194304 + 131072);          // 128 KB
    unsigned char* mask = (unsigned char*)(ws + 4194304 + 262144);  // 8 MB

    k_pack<<<32768, 256, 0, stream>>>(adj, mask);
    k1_gemm<<<512, 256, 0, stream>>>(x, weight, w2, hT, s_src, s_dst);
    k2_attn<<<512, 256, 0, stream>>>(mask, s_src, s_dst, hT, out);
}

// Round 10
// 404.281 us; speedup vs baseline: 1.1117x; 1.0092x over previous
//
#include <hip/hip_runtime.h>
#include <hip/hip_bf16.h>

#define BB 16
#define NN 2048
#define FIN 256
#define FO 64
#define CH 256        // k2 j-chunk
#define HSTR 264      // LDS hT row stride (bf16): pad breaks bank aliasing

typedef __bf16 bf16x8 __attribute__((ext_vector_type(8)));
typedef float  f32x4  __attribute__((ext_vector_type(4)));
typedef int    i32x4  __attribute__((ext_vector_type(4)));
typedef unsigned int uint;

// ---------------- K_PACK: adj int32 -> 1-bit mask (268 MB -> 8.4 MB) ---------
// R4-exact lean stream (measured best): nt dwordx4 loads, 32 B/thread, byte
// stores, 32768 tiny blocks -> max occupancy, no L2 pollution.
__global__ __launch_bounds__(256) void k_pack(const int* __restrict__ adj,
                                              unsigned char* __restrict__ mask) {
    size_t t = (size_t)blockIdx.x * 256 + threadIdx.x;
    const i32x4* ap = (const i32x4*)(adj + t * 8);
    i32x4 a0 = __builtin_nontemporal_load(ap);
    i32x4 a1 = __builtin_nontemporal_load(ap + 1);
    unsigned b = (unsigned)(a0.x > 0) | ((unsigned)(a0.y > 0) << 1) |
                 ((unsigned)(a0.z > 0) << 2) | ((unsigned)(a0.w > 0) << 3) |
                 ((unsigned)(a1.x > 0) << 4) | ((unsigned)(a1.y > 0) << 5) |
                 ((unsigned)(a1.z > 0) << 6) | ((unsigned)(a1.w > 0) << 7);
    mask[t] = (unsigned char)b;
}

// ---------------- K1: h GEMM (MFMA bf16) + exact fp32 s_src/s_dst ------------
__global__ __launch_bounds__(256) void k1_gemm(
    const float* __restrict__ x, const float* __restrict__ weight,
    const float* __restrict__ w2,
    __bf16* __restrict__ hT, float* __restrict__ s_src, float* __restrict__ s_dst) {
    __shared__ __bf16 WtL[FO * 264];
    __shared__ float vsL[FIN], vdL[FIN];
    int t = threadIdx.x;
    {
        const float4* wr = (const float4*)(weight + t * FO);
        float a = 0.f, d = 0.f;
#pragma unroll
        for (int c = 0; c < 16; ++c) {
            float4 v = wr[c];
            int o = c * 4;
            WtL[(o + 0) * 264 + t] = (__bf16)v.x;
            WtL[(o + 1) * 264 + t] = (__bf16)v.y;
            WtL[(o + 2) * 264 + t] = (__bf16)v.z;
            WtL[(o + 3) * 264 + t] = (__bf16)v.w;
            a += v.x * w2[o] + v.y * w2[o + 1] + v.z * w2[o + 2] + v.w * w2[o + 3];
            d += v.x * w2[FO + o] + v.y * w2[FO + o + 1] +
                 v.z * w2[FO + o + 2] + v.w * w2[FO + o + 3];
        }
        vsL[t] = a;
        vdL[t] = d;
    }
    __syncthreads();

    int lane = threadIdx.x & 63, w = threadIdx.x >> 6;
    int quad = lane >> 4, m = lane & 15;
    int Rbase = blockIdx.x * 64 + w * 16;
    int R = Rbase + m;
    const float* xr = x + (long)R * FIN;

    f32x4 acc[4] = {};
    float ps = 0.f, pd = 0.f;

#pragma unroll
    for (int k0 = 0; k0 < FIN; k0 += 32) {
        int kb = k0 + quad * 8;
        float4 x0 = *(const float4*)(xr + kb);
        float4 x1 = *(const float4*)(xr + kb + 4);
        float4 u0 = *(const float4*)(vsL + kb);
        float4 u1 = *(const float4*)(vsL + kb + 4);
        float4 t0 = *(const float4*)(vdL + kb);
        float4 t1 = *(const float4*)(vdL + kb + 4);
        ps += x0.x * u0.x + x0.y * u0.y + x0.z * u0.z + x0.w * u0.w +
              x1.x * u1.x + x1.y * u1.y + x1.z * u1.z + x1.w * u1.w;
        pd += x0.x * t0.x + x0.y * t0.y + x0.z * t0.z + x0.w * t0.w +
              x1.x * t1.x + x1.y * t1.y + x1.z * t1.z + x1.w * t1.w;
        bf16x8 bf = {(__bf16)x0.x, (__bf16)x0.y, (__bf16)x0.z, (__bf16)x0.w,
                     (__bf16)x1.x, (__bf16)x1.y, (__bf16)x1.z, (__bf16)x1.w};
#pragma unroll
        for (int ot = 0; ot < 4; ++ot) {
            bf16x8 af = *(const bf16x8*)(WtL + (ot * 16 + m) * 264 + kb);
            acc[ot] = __builtin_amdgcn_mfma_f32_16x16x32_bf16(af, bf, acc[ot], 0, 0, 0);
        }
    }
    ps += __shfl_xor(ps, 16);
    ps += __shfl_xor(ps, 32);
    pd += __shfl_xor(pd, 16);
    pd += __shfl_xor(pd, 32);
    if (quad == 0) {
        s_src[R] = ps;
        s_dst[R] = pd;
    }
    int b = R >> 11;
    int nb = Rbase & (NN - 1);
#pragma unroll
    for (int ot = 0; ot < 4; ++ot) {
#pragma unroll
        for (int r = 0; r < 4; ++r) {
            int o = ot * 16 + quad * 4 + r;
            hT[((long)b * FO + o) * NN + nb + m] = (__bf16)acc[ot][r];
        }
    }
}

// ---------------- K2: masked-softmax + PV, 2 i-tiles/wave + dbuf LDS ---------
// grid = 16 b * 16 itiles = 256 blocks (1/CU); block = 4 waves = 128 i-rows.
// Each wave computes TWO 16-row i-tiles (rows m and m+16), reusing every hL
// B-fragment for 2 MFMAs: halves total LDS reads AND halves hT global
// re-staging (128 -> 64 MB) vs R9, with no new fragment-layout risk.
// Double-buffered hL: chunk c+1 is reg-prefetched during compute-c and
// ds_written pre-barrier -> ONE barrier per chunk, latency fully covered.
// Numerics (R6+, passing): p = mask ? fmax(EL[j], cK_row) : 0,
// EL[j] = exp(sd_j - mx); E-loads shared by both rows. Denom via ones-MFMA.
__global__ __launch_bounds__(256, 1) void k2_attn(
    const unsigned char* __restrict__ mask, const float* __restrict__ s_src,
    const float* __restrict__ s_dst, const __bf16* __restrict__ hT,
    float* __restrict__ out) {
    __shared__ __bf16 hL[2][FO * HSTR];  // 2 x 33 KB
    __shared__ float EL[NN];             // 8 KB
    int b = blockIdx.x >> 4;
    int i0 = (blockIdx.x & 15) << 7;     // 128 rows per block
    int lane = threadIdx.x & 63, w = threadIdx.x >> 6;
    int quad = lane >> 4, m = lane & 15;
    int rowbase = i0 + w * 32;           // wave covers 32 rows
    int row0 = rowbase + m;
    int row1 = rowbase + 16 + m;

    const float* sd = s_dst + b * NN;
    // per-wave mx (bitwise-identical across waves)
    float mx = -3.0e38f;
    for (int j = lane; j < NN; j += 64) mx = fmaxf(mx, sd[j]);
#pragma unroll
    for (int off = 32; off >= 1; off >>= 1) mx = fmaxf(mx, __shfl_xor(mx, off));
    // cooperative EL fill (visible after the initial __syncthreads)
    {
        int j0 = threadIdx.x * 8;
        float4 v0 = *(const float4*)(sd + j0);
        float4 v1 = *(const float4*)(sd + j0 + 4);
        EL[j0 + 0] = __expf(v0.x - mx);
        EL[j0 + 1] = __expf(v0.y - mx);
        EL[j0 + 2] = __expf(v0.z - mx);
        EL[j0 + 3] = __expf(v0.w - mx);
        EL[j0 + 4] = __expf(v1.x - mx);
        EL[j0 + 5] = __expf(v1.y - mx);
        EL[j0 + 6] = __expf(v1.z - mx);
        EL[j0 + 7] = __expf(v1.w - mx);
    }

    float cK0 = __expf(-(s_src[b * NN + row0] + mx));
    float cK1 = __expf(-(s_src[b * NN + row1] + mx));

    // staging role: thread stages hT row so (0..63), 128 B at col seg (tid&3)*64
    int so = threadIdx.x >> 2;
    int sc = (threadIdx.x & 3) * 64;
    const __bf16* hsrc = hT + ((long)b * FO + so) * NN + sc;
    int ldoff = so * HSTR + sc;

    const uint4* mrow0 = (const uint4*)(mask + ((size_t)(b * NN + row0)) * 256);
    const uint4* mrow1 = (const uint4*)(mask + ((size_t)(b * NN + row1)) * 256);
    int q8 = quad * 8;

    // prefetch chunk 0 (hT fragment + both rows' mask dwords)
    bf16x8 st[8];
    {
        const bf16x8* sp = (const bf16x8*)hsrc;
#pragma unroll
        for (int i = 0; i < 8; ++i) st[i] = sp[i];
    }
    uint4 ma0 = mrow0[0], ma1 = mrow0[1];
    uint4 mb0 = mrow1[0], mb1 = mrow1[1];
    // write buffer 0
    {
        bf16x8* dp = (bf16x8*)(hL[0] + ldoff);
#pragma unroll
        for (int i = 0; i < 8; ++i) dp[i] = st[i];
    }
    __syncthreads();  // buf0 + EL visible

    f32x4 acc0[4] = {}, acc1[4] = {};
    f32x4 accL0 = {}, accL1 = {};
    const bf16x8 ones = {(__bf16)1.f, (__bf16)1.f, (__bf16)1.f, (__bf16)1.f,
                         (__bf16)1.f, (__bf16)1.f, (__bf16)1.f, (__bf16)1.f};

#pragma unroll
    for (int c = 0; c < NN / CH; ++c) {
        const __bf16* cur = hL[c & 1];
        uint mg0[8] = {ma0.x, ma0.y, ma0.z, ma0.w, ma1.x, ma1.y, ma1.z, ma1.w};
        uint mg1[8] = {mb0.x, mb0.y, mb0.z, mb0.w, mb1.x, mb1.y, mb1.z, mb1.w};
        if (c < NN / CH - 1) {
            // prefetch chunk c+1 into registers (consumed at pre-barrier ds_write)
            const bf16x8* sp = (const bf16x8*)(hsrc + (c + 1) * CH);
#pragma unroll
            for (int i = 0; i < 8; ++i) st[i] = sp[i];
            ma0 = mrow0[(c + 1) * 2];
            ma1 = mrow0[(c + 1) * 2 + 1];
            mb0 = mrow1[(c + 1) * 2];
            mb1 = mrow1[(c + 1) * 2 + 1];
        }
        // ---- compute chunk c ----
#pragma unroll
        for (int u = 0; u < 8; ++u) {
            uint mA = (mg0[u] >> q8) & 0xffu;
            uint mB = (mg1[u] >> q8) & 0xffu;
            const float* ep = EL + (c * 8 + u) * 32 + q8;
            float4 e0 = *(const float4*)ep;
            float4 e1 = *(const float4*)(ep + 4);
            float a0 = (mA & 1u)   ? fmaxf(e0.x, cK0) : 0.f;
            float a1 = (mA & 2u)   ? fmaxf(e0.y, cK0) : 0.f;
            float a2 = (mA & 4u)   ? fmaxf(e0.z, cK0) : 0.f;
            float a3 = (mA & 8u)   ? fmaxf(e0.w, cK0) : 0.f;
            float a4 = (mA & 16u)  ? fmaxf(e1.x, cK0) : 0.f;
            float a5 = (mA & 32u)  ? fmaxf(e1.y, cK0) : 0.f;
            float a6 = (mA & 64u)  ? fmaxf(e1.z, cK0) : 0.f;
            float a7 = (mA & 128u) ? fmaxf(e1.w, cK0) : 0.f;
            float b0 = (mB & 1u)   ? fmaxf(e0.x, cK1) : 0.f;
            float b1 = (mB & 2u)   ? fmaxf(e0.y, cK1) : 0.f;
            float b2 = (mB & 4u)   ? fmaxf(e0.z, cK1) : 0.f;
            float b3 = (mB & 8u)   ? fmaxf(e0.w, cK1) : 0.f;
            float b4 = (mB & 16u)  ? fmaxf(e1.x, cK1) : 0.f;
            float b5 = (mB & 32u)  ? fmaxf(e1.y, cK1) : 0.f;
            float b6 = (mB & 64u)  ? fmaxf(e1.z, cK1) : 0.f;
            float b7 = (mB & 128u) ? fmaxf(e1.w, cK1) : 0.f;
            bf16x8 af0 = {(__bf16)a0, (__bf16)a1, (__bf16)a2, (__bf16)a3,
                          (__bf16)a4, (__bf16)a5, (__bf16)a6, (__bf16)a7};
            bf16x8 af1 = {(__bf16)b0, (__bf16)b1, (__bf16)b2, (__bf16)b3,
                          (__bf16)b4, (__bf16)b5, (__bf16)b6, (__bf16)b7};
            accL0 = __builtin_amdgcn_mfma_f32_16x16x32_bf16(af0, ones, accL0, 0, 0, 0);
            accL1 = __builtin_amdgcn_mfma_f32_16x16x32_bf16(af1, ones, accL1, 0, 0, 0);
            const __bf16* hb = cur + u * 32 + q8;
#pragma unroll
            for (int ot = 0; ot < 4; ++ot) {
                bf16x8 bf = *(const bf16x8*)(hb + (ot * 16 + m) * HSTR);
                acc0[ot] = __builtin_amdgcn_mfma_f32_16x16x32_bf16(af0, bf, acc0[ot], 0, 0, 0);
                acc1[ot] = __builtin_amdgcn_mfma_f32_16x16x32_bf16(af1, bf, acc1[ot], 0, 0, 0);
            }
        }
        if (c < NN / CH - 1) {
            // safe: buf[(c+1)&1]'s previous readers finished before the barrier
            // that ended chunk c-1; write new data pre-barrier.
            bf16x8* dp = (bf16x8*)(hL[(c + 1) & 1] + ldoff);
#pragma unroll
            for (int i = 0; i < 8; ++i) dp[i] = st[i];
        }
        __syncthreads();
    }

    // epilogue: D layout col=lane&15 (o), row=quad*4+r (i-local); accL[r]=denom
    float* outp = out + ((long)b * NN + rowbase) * FO;
#pragma unroll
    for (int r = 0; r < 4; ++r) {
        int orow0 = quad * 4 + r;
        float inv0 = 1.0f / accL0[r];
        float inv1 = 1.0f / accL1[r];
#pragma unroll
        for (int ot = 0; ot < 4; ++ot) {
            outp[(long)orow0 * FO + ot * 16 + m] = acc0[ot][r] * inv0;
            outp[(long)(orow0 + 16) * FO + ot * 16 + m] = acc1[ot][r] * inv1;
        }
    }
}

extern "C" void kernel_launch(void* const* d_in, const int* in_sizes, int n_in,
                              void* d_out, int out_size, void* d_ws, size_t ws_size,
                              hipStream_t stream) {
    const float* x      = (const float*)d_in[0];
    const int*   adj    = (const int*)d_in[1];
    const float* weight = (const float*)d_in[2];
    const float* w2     = (const float*)d_in[3];
    float* out = (float*)d_out;

    char* ws = (char*)d_ws;
    __bf16* hT   = (__bf16*)ws;                              // 4 MB
    float* s_src = (float*)(ws + 4194304);                   // 128 KB
    float* s_dst = (float*)(ws + 4194304 + 131072);          // 128 KB
    unsigned char* mask = (unsigned char*)(ws + 4194304 + 262144);  // 8 MB

    k_pack<<<32768, 256, 0, stream>>>(adj, mask);
    k1_gemm<<<512, 256, 0, stream>>>(x, weight, w2, hT, s_src, s_dst);
    k2_attn<<<256, 256, 0, stream>>>(mask, s_src, s_dst, hT, out);
}

// Round 11
// 394.570 us; speedup vs baseline: 1.1391x; 1.0246x over previous
//
#include <hip/hip_runtime.h>
#include <hip/hip_bf16.h>

#define BB 16
#define NN 2048
#define FIN 256
#define FO 64
#define CH 256        // k2 j-chunk
#define HSTR 264      // LDS hT row stride (bf16): pad breaks bank aliasing

typedef __bf16 bf16x8 __attribute__((ext_vector_type(8)));
typedef float  f32x4  __attribute__((ext_vector_type(4)));
typedef int    i32x4  __attribute__((ext_vector_type(4)));
typedef unsigned int uint;

// ---------------- K1: h GEMM (MFMA bf16) + exact fp32 s_src/s_dst ------------
__global__ __launch_bounds__(256) void k1_gemm(
    const float* __restrict__ x, const float* __restrict__ weight,
    const float* __restrict__ w2,
    __bf16* __restrict__ hT, float* __restrict__ s_src, float* __restrict__ s_dst) {
    __shared__ __bf16 WtL[FO * 264];
    __shared__ float vsL[FIN], vdL[FIN];
    int t = threadIdx.x;
    {
        const float4* wr = (const float4*)(weight + t * FO);
        float a = 0.f, d = 0.f;
#pragma unroll
        for (int c = 0; c < 16; ++c) {
            float4 v = wr[c];
            int o = c * 4;
            WtL[(o + 0) * 264 + t] = (__bf16)v.x;
            WtL[(o + 1) * 264 + t] = (__bf16)v.y;
            WtL[(o + 2) * 264 + t] = (__bf16)v.z;
            WtL[(o + 3) * 264 + t] = (__bf16)v.w;
            a += v.x * w2[o] + v.y * w2[o + 1] + v.z * w2[o + 2] + v.w * w2[o + 3];
            d += v.x * w2[FO + o] + v.y * w2[FO + o + 1] +
                 v.z * w2[FO + o + 2] + v.w * w2[FO + o + 3];
        }
        vsL[t] = a;
        vdL[t] = d;
    }
    __syncthreads();

    int lane = threadIdx.x & 63, w = threadIdx.x >> 6;
    int quad = lane >> 4, m = lane & 15;
    int Rbase = blockIdx.x * 64 + w * 16;
    int R = Rbase + m;
    const float* xr = x + (long)R * FIN;

    f32x4 acc[4] = {};
    float ps = 0.f, pd = 0.f;

#pragma unroll
    for (int k0 = 0; k0 < FIN; k0 += 32) {
        int kb = k0 + quad * 8;
        float4 x0 = *(const float4*)(xr + kb);
        float4 x1 = *(const float4*)(xr + kb + 4);
        float4 u0 = *(const float4*)(vsL + kb);
        float4 u1 = *(const float4*)(vsL + kb + 4);
        float4 t0 = *(const float4*)(vdL + kb);
        float4 t1 = *(const float4*)(vdL + kb + 4);
        ps += x0.x * u0.x + x0.y * u0.y + x0.z * u0.z + x0.w * u0.w +
              x1.x * u1.x + x1.y * u1.y + x1.z * u1.z + x1.w * u1.w;
        pd += x0.x * t0.x + x0.y * t0.y + x0.z * t0.z + x0.w * t0.w +
              x1.x * t1.x + x1.y * t1.y + x1.z * t1.z + x1.w * t1.w;
        bf16x8 bf = {(__bf16)x0.x, (__bf16)x0.y, (__bf16)x0.z, (__bf16)x0.w,
                     (__bf16)x1.x, (__bf16)x1.y, (__bf16)x1.z, (__bf16)x1.w};
#pragma unroll
        for (int ot = 0; ot < 4; ++ot) {
            bf16x8 af = *(const bf16x8*)(WtL + (ot * 16 + m) * 264 + kb);
            acc[ot] = __builtin_amdgcn_mfma_f32_16x16x32_bf16(af, bf, acc[ot], 0, 0, 0);
        }
    }
    ps += __shfl_xor(ps, 16);
    ps += __shfl_xor(ps, 32);
    pd += __shfl_xor(pd, 16);
    pd += __shfl_xor(pd, 32);
    if (quad == 0) {
        s_src[R] = ps;
        s_dst[R] = pd;
    }
    int b = R >> 11;
    int nb = Rbase & (NN - 1);
#pragma unroll
    for (int ot = 0; ot < 4; ++ot) {
#pragma unroll
        for (int r = 0; r < 4; ++r) {
            int o = ot * 16 + quad * 4 + r;
            hT[((long)b * FO + o) * NN + nb + m] = (__bf16)acc[ot][r];
        }
    }
}

// ---------------- K2: FUSED adj-stream + masked-softmax + PV -----------------
// Replaces k_pack + mask entirely. grid = 16 b * 32 itiles = 512 blocks
// (2/CU: 74 KB LDS, VGPR<=256 via launch_bounds(256,2)); block = 4 waves =
// 64 i-rows. Per 256-j chunk each lane register-prefetches its OWN adj slice
// (row rowbase+m, quad's j-lanes: 16 x i32x4 = 64 ints) for chunk c+1 while
// chunk c computes — the R9/R10 pipeline pattern applied to the 268 MB adj
// stream. Per CU per chunk: 128 KB adj = ~12400 cyc HBM drain vs ~2000 cyc
// compute -> kernel is HBM-bound; the vmcnt(0)-at-barrier only relocates the
// wait (loads stay in flight), it cannot idle the HBM pipe.
// hL: double-buffered hT chunk staging (R10); EL/cK numerics (R6+, passing):
// p = (adj>0) ? fmax(EL[j], cK) : 0. Denominator via ones-MFMA.
__global__ __launch_bounds__(256, 2) void k2_attn(
    const int* __restrict__ adj, const float* __restrict__ s_src,
    const float* __restrict__ s_dst, const __bf16* __restrict__ hT,
    float* __restrict__ out) {
    __shared__ __bf16 hL[2][FO * HSTR];  // 2 x 33 KB
    __shared__ float EL[NN];             // 8 KB
    int b = blockIdx.x >> 5;
    int i0 = (blockIdx.x & 31) << 6;
    int lane = threadIdx.x & 63, w = threadIdx.x >> 6;
    int quad = lane >> 4, m = lane & 15;
    int rowbase = i0 + w * 16;
    int row = rowbase + m;

    const float* sd = s_dst + b * NN;
    // per-wave mx (bitwise-identical across waves)
    float mx = -3.0e38f;
    for (int j = lane; j < NN; j += 64) mx = fmaxf(mx, sd[j]);
#pragma unroll
    for (int off = 32; off >= 1; off >>= 1) mx = fmaxf(mx, __shfl_xor(mx, off));
    // cooperative EL fill (visible after the initial __syncthreads)
    {
        int j0 = threadIdx.x * 8;
        float4 v0 = *(const float4*)(sd + j0);
        float4 v1 = *(const float4*)(sd + j0 + 4);
        EL[j0 + 0] = __expf(v0.x - mx);
        EL[j0 + 1] = __expf(v0.y - mx);
        EL[j0 + 2] = __expf(v0.z - mx);
        EL[j0 + 3] = __expf(v0.w - mx);
        EL[j0 + 4] = __expf(v1.x - mx);
        EL[j0 + 5] = __expf(v1.y - mx);
        EL[j0 + 6] = __expf(v1.z - mx);
        EL[j0 + 7] = __expf(v1.w - mx);
    }

    float cK = __expf(-(s_src[b * NN + row] + mx));  // relu floor, scaled space

    // adj base for this lane's row, in i32x4 units; k-step ks covers
    // j = ks*32 + q8 .. +8  ->  i32x4 indices ks*8 + quad*2, +1
    const i32x4* arow = (const i32x4*)(adj + ((size_t)(b * NN + row)) * NN);
    int aq = quad * 2;

    // hT staging role: thread stages o-row (tid>>2), 128 B at col (tid&3)*64
    int so = threadIdx.x >> 2;
    int sc = (threadIdx.x & 3) * 64;
    const __bf16* hsrc = hT + ((long)b * FO + so) * NN + sc;
    int ldoff = so * HSTR + sc;
    int q8 = quad * 8;

    // ---- prefetch chunk 0: adj (16 x i32x4) + hT (8 x bf16x8) ----
    i32x4 A[16];
#pragma unroll
    for (int u = 0; u < 8; ++u) {
        A[2 * u]     = arow[u * 8 + aq];
        A[2 * u + 1] = arow[u * 8 + aq + 1];
    }
    bf16x8 st[8];
    {
        const bf16x8* sp = (const bf16x8*)hsrc;
#pragma unroll
        for (int i = 0; i < 8; ++i) st[i] = sp[i];
    }
    {
        bf16x8* dp = (bf16x8*)(hL[0] + ldoff);
#pragma unroll
        for (int i = 0; i < 8; ++i) dp[i] = st[i];
    }
    __syncthreads();  // buf0 + EL visible

    f32x4 acc[4] = {};
    f32x4 accL = {};
    const bf16x8 ones = {(__bf16)1.f, (__bf16)1.f, (__bf16)1.f, (__bf16)1.f,
                         (__bf16)1.f, (__bf16)1.f, (__bf16)1.f, (__bf16)1.f};

    for (int c = 0; c < NN / CH; ++c) {
        const __bf16* cur = hL[c & 1];
        // ---- build all A-fragments for chunk c from adj regs + EL ----
        bf16x8 af[8];
#pragma unroll
        for (int u = 0; u < 8; ++u) {
            const float* ep = EL + (c * 8 + u) * 32 + q8;
            float4 e0 = *(const float4*)ep;
            float4 e1 = *(const float4*)(ep + 4);
            i32x4 a0 = A[2 * u], a1 = A[2 * u + 1];
            float p0 = (a0.x > 0) ? fmaxf(e0.x, cK) : 0.f;
            float p1 = (a0.y > 0) ? fmaxf(e0.y, cK) : 0.f;
            float p2 = (a0.z > 0) ? fmaxf(e0.z, cK) : 0.f;
            float p3 = (a0.w > 0) ? fmaxf(e0.w, cK) : 0.f;
            float p4 = (a1.x > 0) ? fmaxf(e1.x, cK) : 0.f;
            float p5 = (a1.y > 0) ? fmaxf(e1.y, cK) : 0.f;
            float p6 = (a1.z > 0) ? fmaxf(e1.z, cK) : 0.f;
            float p7 = (a1.w > 0) ? fmaxf(e1.w, cK) : 0.f;
            af[u] = bf16x8{(__bf16)p0, (__bf16)p1, (__bf16)p2, (__bf16)p3,
                           (__bf16)p4, (__bf16)p5, (__bf16)p6, (__bf16)p7};
        }
        // ---- issue chunk c+1 prefetches (adj regs now free; consumed below) --
        if (c < NN / CH - 1) {
            const i32x4* an = arow + (c + 1) * 64;  // (c+1)*8*8 i32x4 per 8 ksteps
#pragma unroll
            for (int u = 0; u < 8; ++u) {
                A[2 * u]     = an[u * 8 + aq];
                A[2 * u + 1] = an[u * 8 + aq + 1];
            }
            const bf16x8* sp = (const bf16x8*)(hsrc + (c + 1) * CH);
#pragma unroll
            for (int i = 0; i < 8; ++i) st[i] = sp[i];
        }
        // ---- MFMA phase chunk c ----
#pragma unroll
        for (int u = 0; u < 8; ++u) {
            accL = __builtin_amdgcn_mfma_f32_16x16x32_bf16(af[u], ones, accL, 0, 0, 0);
            const __bf16* hb = cur + u * 32 + q8;
#pragma unroll
            for (int ot = 0; ot < 4; ++ot) {
                bf16x8 bf = *(const bf16x8*)(hb + (ot * 16 + m) * HSTR);
                acc[ot] = __builtin_amdgcn_mfma_f32_16x16x32_bf16(af[u], bf, acc[ot], 0, 0, 0);
            }
        }
        // ---- stage chunk c+1 into the other buffer, then one barrier ----
        if (c < NN / CH - 1) {
            bf16x8* dp = (bf16x8*)(hL[(c + 1) & 1] + ldoff);
#pragma unroll
            for (int i = 0; i < 8; ++i) dp[i] = st[i];
        }
        __syncthreads();
    }

    // epilogue: D layout col=lane&15 (o), row=quad*4+r (i-local); accL[r]=denom
    float* outp = out + ((long)b * NN + rowbase) * FO;
#pragma unroll
    for (int r = 0; r < 4; ++r) {
        int orow = quad * 4 + r;
        float inv = 1.0f / accL[r];
#pragma unroll
        for (int ot = 0; ot < 4; ++ot) {
            outp[(long)orow * FO + ot * 16 + m] = acc[ot][r] * inv;
        }
    }
}

extern "C" void kernel_launch(void* const* d_in, const int* in_sizes, int n_in,
                              void* d_out, int out_size, void* d_ws, size_t ws_size,
                              hipStream_t stream) {
    const float* x      = (const float*)d_in[0];
    const int*   adj    = (const int*)d_in[1];
    const float* weight = (const float*)d_in[2];
    const float* w2     = (const float*)d_in[3];
    float* out = (float*)d_out;

    char* ws = (char*)d_ws;
    __bf16* hT   = (__bf16*)ws;                              // 4 MB
    float* s_src = (float*)(ws + 4194304);                   // 128 KB
    float* s_dst = (float*)(ws + 4194304 + 131072);          // 128 KB

    k1_gemm<<<512, 256, 0, stream>>>(x, weight, w2, hT, s_src, s_dst);
    k2_attn<<<512, 256, 0, stream>>>(adj, s_src, s_dst, hT, out);
}